// Round 12
// baseline (264.855 us; speedup 1.0000x reference)
//
#include <hip/hip_runtime.h>
#include <hip/hip_bf16.h>

typedef __attribute__((ext_vector_type(8))) short short8;
typedef __attribute__((ext_vector_type(2))) float f32x2;
typedef __attribute__((ext_vector_type(4))) float f32x4;
typedef __attribute__((ext_vector_type(16))) float f32x16;

static constexpr int DM = 1024;   // d_model
static constexpr int NH = 16;     // heads
static constexpr int DK = 64;     // head dim
static constexpr int SL = 2048;   // seq len
static constexpr int BB = 4;      // batch
static constexpr size_t QKV_ELEMS = (size_t)BB * NH * SL * DK;  // 8388608
static constexpr float NEG_BIG = -30000.0f;          // exp2 -> 0
static constexpr float SC_LOG2E = 0.125f * 1.44269504088896340736f; // /sqrt(64)*log2(e)

union PackB { __hip_bfloat16 h[8]; uint4 u; };
union Pack4 { __hip_bfloat16 h[4]; uint2 u; };

// async global->LDS, 16 B per lane (dest = wave-uniform base + lane*16)
typedef __attribute__((address_space(1))) unsigned int gu32;
typedef __attribute__((address_space(3))) unsigned int lu32;
__device__ __forceinline__ void async_copy16(const void* g, void* l) {
    __builtin_amdgcn_global_load_lds((gu32*)g, (lu32*)l, 16, 0, 0);
}

// pack two f32 -> two bf16 in one u32 (low = first arg)
__device__ __forceinline__ unsigned cvt_pk_bf16(float lo, float hi) {
    unsigned r;
    asm("v_cvt_pk_bf16_f32 %0, %1, %2" : "=v"(r) : "v"(lo), "v"(hi));
    return r;
}
// swap: a.hi <-> b.lo  (new_a[l>=32]=b[l-32], new_b[l<32]=a[l+32])
__device__ __forceinline__ void pl32_swap(unsigned &a, unsigned &b) {
    asm("v_permlane32_swap_b32 %0, %1" : "+v"(a), "+v"(b));
}

// ---------------------------------------------------------------------------
// Bulk fp32 -> bf16 convert: x (8M elems) then Wq,Wk,Wv,Wo (1M each) into one
// contiguous bf16 region. One float4 per thread.
// ---------------------------------------------------------------------------
__global__ __launch_bounds__(256)
void cvt_all(const float* __restrict__ x,
             const float* __restrict__ wq, const float* __restrict__ wk,
             const float* __restrict__ wv, const float* __restrict__ wo,
             __hip_bfloat16* __restrict__ dst)
{
    const size_t i = (size_t)blockIdx.x * 256 + threadIdx.x;  // float4 index
    const float* src; size_t local;
    if (i < 2097152) { src = x; local = i; }
    else {
        const size_t j = i - 2097152;
        const int r = (int)(j >> 18);           // 262144 float4 per W
        local = j & 262143;
        src = (r == 0) ? wq : (r == 1) ? wk : (r == 2) ? wv : wo;
    }
    float4 f = reinterpret_cast<const float4*>(src)[local];
    Pack4 p;
    p.h[0] = __float2bfloat16(f.x); p.h[1] = __float2bfloat16(f.y);
    p.h[2] = __float2bfloat16(f.z); p.h[3] = __float2bfloat16(f.w);
    reinterpret_cast<uint2*>(dst)[i] = p.u;
}

// ---------------------------------------------------------------------------
// Fused QKV projection, BK=64, 2-phase double-buffered, 128^2 / 256 thr
// (FROZEN — measured 82.6-84.9 us). Q PRE-SCALED by SC_LOG2E.
// ---------------------------------------------------------------------------
__global__ __launch_bounds__(256)
void gemm_qkv(const __hip_bfloat16* __restrict__ A,
              const __hip_bfloat16* __restrict__ W,
              __hip_bfloat16* __restrict__ q_out,
              __hip_bfloat16* __restrict__ k_out,
              __hip_bfloat16* __restrict__ v_out)
{
    __shared__ __hip_bfloat16 As[2][128 * 64];
    __shared__ __hip_bfloat16 Bs[2][128 * 64];
    const int tid  = threadIdx.x;
    const int m0   = blockIdx.x * 128;
    const int n0   = blockIdx.y * 128;
    const int w    = tid >> 6;
    const int lane = tid & 63;
    const int quad = lane >> 4;
    const int ln   = lane & 15;
    const int wm   = (w & 1) * 64;
    const int wn   = (w >> 1) * 64;
    const int srow = lane >> 3;                    // 0..7
    const int sch  = ((lane & 7) ^ srow) * 8;      // swizzled source chunk

    f32x4 acc[4][4] = {};

    auto stage = [&](int buf, int k0) {
        #pragma unroll
        for (int j = 0; j < 4; j++) {
            const int rbase = w * 32 + j * 8;      // stripe-aligned
            async_copy16(A + (size_t)(m0 + rbase + srow) * DM + k0 + sch,
                         &As[buf][rbase * 64]);
            async_copy16(W + (size_t)(n0 + rbase + srow) * DM + k0 + sch,
                         &Bs[buf][rbase * 64]);
        }
    };

    constexpr int NT = DM / 64;   // 16
    stage(0, 0);
    asm volatile("s_waitcnt vmcnt(0)" ::: "memory");
    __syncthreads();

    int cur = 0;
    for (int t = 0; t < NT; ++t) {
        if (t + 1 < NT) stage(cur ^ 1, (t + 1) * 64);

        #pragma unroll
        for (int ks = 0; ks < 2; ks++) {
            short8 a[4], b[4];
            #pragma unroll
            for (int i = 0; i < 4; i++)
                a[i] = *reinterpret_cast<const short8*>(
                    &As[cur][(wm + i*16 + ln) * 64 + (((ks*4 + quad) ^ (ln & 7)) * 8)]);
            #pragma unroll
            for (int j = 0; j < 4; j++)
                b[j] = *reinterpret_cast<const short8*>(
                    &Bs[cur][(wn + j*16 + ln) * 64 + (((ks*4 + quad) ^ (ln & 7)) * 8)]);
            __builtin_amdgcn_s_setprio(1);
            #pragma unroll
            for (int i = 0; i < 4; i++)
                #pragma unroll
                for (int j = 0; j < 4; j++)
                    acc[i][j] = __builtin_amdgcn_mfma_f32_16x16x32_bf16(a[i], b[j], acc[i][j], 0, 0, 0);
            __builtin_amdgcn_s_setprio(0);
        }

        if (t + 1 < NT) {
            asm volatile("s_waitcnt vmcnt(0)" ::: "memory");
            __syncthreads();
        }
        cur ^= 1;
    }

    // Epilogue: C/D layout col=lane&15, row=quad*4+reg  [m89/m91]
    #pragma unroll
    for (int i = 0; i < 4; i++) {
        #pragma unroll
        for (int j = 0; j < 4; j++) {
            #pragma unroll
            for (int r = 0; r < 4; r++) {
                const int m = m0 + wm + i*16 + quad*4 + r;
                const int n = n0 + wn + j*16 + ln;     // 0..3071
                const int b_ = m >> 11;
                const int s  = m & 2047;
                const int which = n >> 10;             // 0=Q 1=K 2=V
                const int nn = n & 1023;
                const int h  = nn >> 6;
                const int d  = nn & 63;
                if (which == 0) {
                    const __hip_bfloat16 v = __float2bfloat16(acc[i][j][r] * SC_LOG2E);
                    q_out[((size_t)((b_*NH + h)*SL + s))*DK + d] = v;
                } else if (which == 1) {
                    const __hip_bfloat16 v = __float2bfloat16(acc[i][j][r]);
                    k_out[((size_t)((b_*NH + h)*SL + s))*DK + d] = v;
                } else {
                    const __hip_bfloat16 v = __float2bfloat16(acc[i][j][r]);
                    v_out[((size_t)((b_*NH + h)*DK + d))*SL + s] = v;
                }
            }
        }
    }
}

// ---------------------------------------------------------------------------
// Pure-bf16 GEMM (final projection), 2-phase dbuf (frozen).
// ---------------------------------------------------------------------------
__global__ __launch_bounds__(256)
void gemm_wo(const __hip_bfloat16* __restrict__ A,
             const __hip_bfloat16* __restrict__ W,
             float* __restrict__ outp)
{
    __shared__ __hip_bfloat16 As[2][128 * 64];
    __shared__ __hip_bfloat16 Bs[2][128 * 64];
    const int tid  = threadIdx.x;
    const int m0   = blockIdx.x * 128;
    const int n0   = blockIdx.y * 128;
    const int w    = tid >> 6;
    const int lane = tid & 63;
    const int quad = lane >> 4;
    const int ln   = lane & 15;
    const int wm   = (w & 1) * 64;
    const int wn   = (w >> 1) * 64;
    const int srow = lane >> 3;
    const int sch  = ((lane & 7) ^ srow) * 8;

    f32x4 acc[4][4] = {};

    auto stage = [&](int buf, int k0) {
        #pragma unroll
        for (int j = 0; j < 4; j++) {
            const int rbase = w * 32 + j * 8;
            async_copy16(A + (size_t)(m0 + rbase + srow) * DM + k0 + sch,
                         &As[buf][rbase * 64]);
            async_copy16(W + (size_t)(n0 + rbase + srow) * DM + k0 + sch,
                         &Bs[buf][rbase * 64]);
        }
    };

    constexpr int NT = DM / 64;
    stage(0, 0);
    asm volatile("s_waitcnt vmcnt(0)" ::: "memory");
    __syncthreads();

    int cur = 0;
    for (int t = 0; t < NT; ++t) {
        if (t + 1 < NT) stage(cur ^ 1, (t + 1) * 64);

        #pragma unroll
        for (int ks = 0; ks < 2; ks++) {
            short8 a[4], b[4];
            #pragma unroll
            for (int i = 0; i < 4; i++)
                a[i] = *reinterpret_cast<const short8*>(
                    &As[cur][(wm + i*16 + ln) * 64 + (((ks*4 + quad) ^ (ln & 7)) * 8)]);
            #pragma unroll
            for (int j = 0; j < 4; j++)
                b[j] = *reinterpret_cast<const short8*>(
                    &Bs[cur][(wn + j*16 + ln) * 64 + (((ks*4 + quad) ^ (ln & 7)) * 8)]);
            __builtin_amdgcn_s_setprio(1);
            #pragma unroll
            for (int i = 0; i < 4; i++)
                #pragma unroll
                for (int j = 0; j < 4; j++)
                    acc[i][j] = __builtin_amdgcn_mfma_f32_16x16x32_bf16(a[i], b[j], acc[i][j], 0, 0, 0);
            __builtin_amdgcn_s_setprio(0);
        }

        if (t + 1 < NT) {
            asm volatile("s_waitcnt vmcnt(0)" ::: "memory");
            __syncthreads();
        }
        cur ^= 1;
    }

    #pragma unroll
    for (int i = 0; i < 4; i++)
        #pragma unroll
        for (int j = 0; j < 4; j++)
            #pragma unroll
            for (int r = 0; r < 4; r++) {
                const int m = m0 + wm + i*16 + quad*4 + r;
                const int n = n0 + wn + j*16 + ln;
                outp[(size_t)m * DM + n] = acc[i][j][r];
            }
}

// ---------------------------------------------------------------------------
// Fallback GEMM: fp32 inputs, convert during staging. scl folds the softmax
// scale into Q (attn expects pre-scaled Q).
// ---------------------------------------------------------------------------
template<bool A_BF16, int MODE>
__global__ __launch_bounds__(256)
void gemm_bt(const void* __restrict__ Ap,
             const float* __restrict__ W,
             void* __restrict__ outp, float scl)
{
    __shared__ __hip_bfloat16 As[128][40];
    __shared__ __hip_bfloat16 Bs[128][40];
    const int tid  = threadIdx.x;
    const int m0   = blockIdx.x * 128;
    const int n0   = blockIdx.y * 128;
    const int w    = tid >> 6;
    const int lane = tid & 63;
    const int quad = lane >> 4;
    const int ln   = lane & 15;
    const int wm   = (w & 1) * 64;
    const int wn   = (w >> 1) * 64;
    const int lr   = tid >> 1;
    const int lc   = (tid & 1) * 16;

    f32x4 acc[4][4] = {};

    for (int k0 = 0; k0 < DM; k0 += 32) {
        if (A_BF16) {
            const uint4* ap = reinterpret_cast<const uint4*>(
                (const __hip_bfloat16*)Ap + (size_t)(m0 + lr) * DM + k0 + lc);
            uint4 a0 = ap[0], a1 = ap[1];
            *reinterpret_cast<uint4*>(&As[lr][lc])     = a0;
            *reinterpret_cast<uint4*>(&As[lr][lc + 8]) = a1;
        } else {
            const float4* ap = reinterpret_cast<const float4*>(
                (const float*)Ap + (size_t)(m0 + lr) * DM + k0 + lc);
            float4 f0 = ap[0], f1 = ap[1], f2 = ap[2], f3 = ap[3];
            PackB p0, p1;
            p0.h[0] = __float2bfloat16(f0.x); p0.h[1] = __float2bfloat16(f0.y);
            p0.h[2] = __float2bfloat16(f0.z); p0.h[3] = __float2bfloat16(f0.w);
            p0.h[4] = __float2bfloat16(f1.x); p0.h[5] = __float2bfloat16(f1.y);
            p0.h[6] = __float2bfloat16(f1.z); p0.h[7] = __float2bfloat16(f1.w);
            p1.h[0] = __float2bfloat16(f2.x); p1.h[1] = __float2bfloat16(f2.y);
            p1.h[2] = __float2bfloat16(f2.z); p1.h[3] = __float2bfloat16(f2.w);
            p1.h[4] = __float2bfloat16(f3.x); p1.h[5] = __float2bfloat16(f3.y);
            p1.h[6] = __float2bfloat16(f3.z); p1.h[7] = __float2bfloat16(f3.w);
            *reinterpret_cast<uint4*>(&As[lr][lc])     = p0.u;
            *reinterpret_cast<uint4*>(&As[lr][lc + 8]) = p1.u;
        }
        {
            const float4* wp = reinterpret_cast<const float4*>(
                W + (size_t)(n0 + lr) * DM + k0 + lc);
            float4 f0 = wp[0], f1 = wp[1], f2 = wp[2], f3 = wp[3];
            PackB p0, p1;
            p0.h[0] = __float2bfloat16(f0.x); p0.h[1] = __float2bfloat16(f0.y);
            p0.h[2] = __float2bfloat16(f0.z); p0.h[3] = __float2bfloat16(f0.w);
            p0.h[4] = __float2bfloat16(f1.x); p0.h[5] = __float2bfloat16(f1.y);
            p0.h[6] = __float2bfloat16(f1.z); p0.h[7] = __float2bfloat16(f1.w);
            p1.h[0] = __float2bfloat16(f2.x); p1.h[1] = __float2bfloat16(f2.y);
            p1.h[2] = __float2bfloat16(f2.z); p1.h[3] = __float2bfloat16(f2.w);
            p1.h[4] = __float2bfloat16(f3.x); p1.h[5] = __float2bfloat16(f3.y);
            p1.h[6] = __float2bfloat16(f3.z); p1.h[7] = __float2bfloat16(f3.w);
            *reinterpret_cast<uint4*>(&Bs[lr][lc])     = p0.u;
            *reinterpret_cast<uint4*>(&Bs[lr][lc + 8]) = p1.u;
        }
        __syncthreads();

        short8 a[4], b[4];
        #pragma unroll
        for (int i = 0; i < 4; i++)
            a[i] = *reinterpret_cast<const short8*>(&As[wm + i*16 + ln][quad*8]);
        #pragma unroll
        for (int j = 0; j < 4; j++)
            b[j] = *reinterpret_cast<const short8*>(&Bs[wn + j*16 + ln][quad*8]);
        #pragma unroll
        for (int i = 0; i < 4; i++)
            #pragma unroll
            for (int j = 0; j < 4; j++)
                acc[i][j] = __builtin_amdgcn_mfma_f32_16x16x32_bf16(a[i], b[j], acc[i][j], 0, 0, 0);
        __syncthreads();
    }

    #pragma unroll
    for (int i = 0; i < 4; i++) {
        #pragma unroll
        for (int j = 0; j < 4; j++) {
            #pragma unroll
            for (int r = 0; r < 4; r++) {
                const int m = m0 + wm + i*16 + quad*4 + r;
                const int n = n0 + wn + j*16 + ln;
                const float v = acc[i][j][r] * scl;
                if (MODE == 2) {
                    ((float*)outp)[(size_t)m * DM + n] = v;
                } else {
                    const int b_ = m >> 11;
                    const int s  = m & 2047;
                    const int h  = n >> 6;
                    const int d  = n & 63;
                    size_t idx;
                    if (MODE == 0) idx = ((size_t)((b_*NH + h)*SL + s))*DK + d;
                    else           idx = ((size_t)((b_*NH + h)*DK + d))*SL + s;
                    ((__hip_bfloat16*)outp)[idx] = __float2bfloat16(v);
                }
            }
        }
    }
}

// ---------------------------------------------------------------------------
// Causal flash attention, 32x32 swapped-operand form.
// Round-12: 3-blocks/CU TLP (round-10's direction, minus its spill bug).
//  - LDS 48 KB: K double-buffered (2x16 KB) + V SINGLE-buffered (16 KB)
//    -> 3 blocks/CU LDS-wise (144 <= 160 KB).
//  - NO launch_bounds occupancy cap (VGPR ~140 -> 3 waves/SIMD naturally;
//    round-10's (256,4) forced VGPR=64 and spilled the accumulators).
//  - Single-pass grid (16,64)=1024 blocks, LPT (largest qt first) + fine XCD
//    remap (round-10 measured FETCH 37.7 MB ~ compulsory with this map).
//  - Pipeline per iter (2 barriers): [vmcnt(0)+bar: K(ip) ready, Vs free]
//    issue V(ip) then K(ip+1) -> QK on K(ip) -> softmax (covers V latency)
//    -> [vmcnt(4)+bar: V ready, K(ip+1) stays in flight across PV] -> PV.
//    hf0 is never causally masked, so all waves reach the mid-iter barrier.
// ---------------------------------------------------------------------------
__global__ __launch_bounds__(256)
void attn_causal(const __hip_bfloat16* __restrict__ Q,
                 const __hip_bfloat16* __restrict__ K,
                 const __hip_bfloat16* __restrict__ Vt,
                 __hip_bfloat16* __restrict__ O)
{
    __shared__ __hip_bfloat16 Ks[2][128 * 64];   // [k][d] linear, src-swizzled
    __shared__ __hip_bfloat16 Vs[64 * 128];      // [d][k] linear, src-swizzled

    const int tid  = threadIdx.x;
    const int w    = tid >> 6;
    const int lane = tid & 63;
    const int ln32 = lane & 31;
    const int hi   = lane >> 5;

    // XCD-locality remap over 1024 blocks (bijective):
    // xcd = dd&7, k = dd>>3; qt = 15-(k&15) (largest-first LPT), bh = xcd+8*(k>>4)
    const int dd   = (int)blockIdx.y * 16 + (int)blockIdx.x;
    const int xcd  = dd & 7;
    const int kk   = dd >> 3;
    const int qt   = 15 - (kk & 15);
    const int bh   = xcd + 8 * (kk >> 4);

    const int b_   = bh >> 4;
    const int h    = bh & 15;

    const __hip_bfloat16* Qb = Q  + (size_t)bh * SL * DK;
    const __hip_bfloat16* Kb = K  + (size_t)bh * SL * DK;
    const __hip_bfloat16* Vb = Vt + (size_t)bh * DK * SL;

    auto stageK = [&](int buf, int k0) {
        #pragma unroll
        for (int j = 0; j < 4; j++) {            // K: 128 rows x 64
            const int rb = w * 32 + j * 8;
            const int r  = rb + (lane >> 3);
            async_copy16(Kb + (size_t)(k0 + r) * DK + (((lane & 7) ^ (r & 7)) * 8),
                         &Ks[buf][rb * 64]);
        }
    };
    auto stageV = [&](int k0) {
        #pragma unroll
        for (int j = 0; j < 4; j++) {            // V: 64 rows x 128
            const int db = w * 16 + j * 4;
            const int d  = db + (lane >> 4);
            async_copy16(Vb + (size_t)d * SL + k0 + (((lane & 15) ^ (d & 7)) * 8),
                         &Vs[db * 128]);
        }
    };

    const int q0    = qt * 128;
    const int qbase = q0 + w * 32;
    const int qg    = qbase + ln32;       // this lane's q row

    short8 qf[4];
    #pragma unroll
    for (int dt = 0; dt < 4; dt++)
        qf[dt] = *reinterpret_cast<const short8*>(
            Qb + (size_t)qg * DK + dt*16 + hi*8);

    f32x16 o0 = {}, o1 = {};
    f32x2 ls2 = {0.f, 0.f};

    const int npair = qt + 1;            // 128-k pairs

    stageK(0, 0);                        // prologue: K(0) in flight

    for (int ip = 0; ip < npair; ++ip) {
        const int cur = ip & 1;
        const int k0  = ip * 128;

        // K(ip) ready for all waves; Vs free (prev PV reads done)
        asm volatile("s_waitcnt vmcnt(0)" ::: "memory");
        __builtin_amdgcn_sched_barrier(0);
        __builtin_amdgcn_s_barrier();
        __builtin_amdgcn_sched_barrier(0);

        // issue V(ip) first, then K(ip+1): vmcnt(4) later drains V only
        stageV(k0);
        if (ip + 1 < npair) stageK(cur ^ 1, (ip + 1) * 128);

        #pragma unroll
        for (int hf = 0; hf < 2; hf++) {
            const int kh0 = k0 + hf * 64;
            if (kh0 > qbase + 31) continue;   // wave-uniform (hf1 only)

            // ---- QK^T (swapped): S[k][q]; Q pre-scaled ----
            f32x16 s0 = {}, s1 = {};
            __builtin_amdgcn_s_setprio(1);
            #pragma unroll
            for (int dt = 0; dt < 4; dt++) {
                const int r0 = hf*64 + ln32;
                const int ch = (dt*2 + hi) ^ (ln32 & 7);
                short8 kf0 = *reinterpret_cast<const short8*>(&Ks[cur][r0*64 + ch*8]);
                short8 kf1 = *reinterpret_cast<const short8*>(&Ks[cur][(r0 + 32)*64 + ch*8]);
                s0 = __builtin_amdgcn_mfma_f32_32x32x16_bf16(kf0, qf[dt], s0, 0, 0, 0);
                s1 = __builtin_amdgcn_mfma_f32_32x32x16_bf16(kf1, qf[dt], s1, 0, 0, 0);
            }
            __builtin_amdgcn_s_setprio(0);

            // ---- softmax numerator (in place) ----
            const bool dodiag = (kh0 + 63 > qbase);
            if (dodiag) {
                #pragma unroll
                for (int r = 0; r < 16; r++) {
                    const int km = (r & 3) + 8*(r >> 2) + 4*hi;
                    float v0 = s0[r];
                    float v1 = s1[r];
                    if (kh0 + km      > qg) v0 = NEG_BIG;
                    if (kh0 + 32 + km > qg) v1 = NEG_BIG;
                    const float p0 = __builtin_amdgcn_exp2f(v0);
                    const float p1 = __builtin_amdgcn_exp2f(v1);
                    s0[r] = p0; s1[r] = p1;
                    ls2.x += p0; ls2.y += p1;
                }
            } else {
                #pragma unroll
                for (int r = 0; r < 16; r++) {
                    const float p0 = __builtin_amdgcn_exp2f(s0[r]);
                    const float p1 = __builtin_amdgcn_exp2f(s1[r]);
                    s0[r] = p0; s1[r] = p1;
                    ls2.x += p0; ls2.y += p1;
                }
            }

            // V ready before first PV; K(ip+1) stays in flight across PV
            if (hf == 0) {
                if (ip + 1 < npair) {
                    asm volatile("s_waitcnt vmcnt(4)" ::: "memory");
                } else {
                    asm volatile("s_waitcnt vmcnt(0)" ::: "memory");
                }
                __builtin_amdgcn_sched_barrier(0);
                __builtin_amdgcn_s_barrier();
                __builtin_amdgcn_sched_barrier(0);
            }

            // ---- P fragments (cvt_pk + permlane32_swap) + PV ----
            __builtin_amdgcn_s_setprio(1);
            #pragma unroll
            for (int c = 0; c < 4; c++) {
                const int R = 8 * (c & 1);
                unsigned x0, x1, y0, y1;
                if (c < 2) {
                    x0 = cvt_pk_bf16(s0[R+0], s0[R+1]);
                    x1 = cvt_pk_bf16(s0[R+2], s0[R+3]);
                    y0 = cvt_pk_bf16(s0[R+4], s0[R+5]);
                    y1 = cvt_pk_bf16(s0[R+6], s0[R+7]);
                } else {
                    x0 = cvt_pk_bf16(s1[R+0], s1[R+1]);
                    x1 = cvt_pk_bf16(s1[R+2], s1[R+3]);
                    y0 = cvt_pk_bf16(s1[R+4], s1[R+5]);
                    y1 = cvt_pk_bf16(s1[R+6], s1[R+7]);
                }
                pl32_swap(x0, y0);
                pl32_swap(x1, y1);
                union { unsigned u[4]; short8 s8; } pf;
                pf.u[0] = x0; pf.u[1] = x1; pf.u[2] = y0; pf.u[3] = y1;
                const int vc = (hf*8 + c*2 + hi) ^ (ln32 & 7);
                short8 vf0 = *reinterpret_cast<const short8*>(&Vs[ln32*128 + vc*8]);
                short8 vf1 = *reinterpret_cast<const short8*>(&Vs[(32 + ln32)*128 + vc*8]);
                o0 = __builtin_amdgcn_mfma_f32_32x32x16_bf16(vf0, pf.s8, o0, 0, 0, 0);
                o1 = __builtin_amdgcn_mfma_f32_32x32x16_bf16(vf1, pf.s8, o1, 0, 0, 0);
            }
            __builtin_amdgcn_s_setprio(0);
        }
        // next iter's top vmcnt(0)+barrier guards Vs/Ks overwrite vs this
        // iter's PV/QK reads.
    }

    // full row-sum: this lane's partials + its hi/lo partner
    float lsum = ls2.x + ls2.y;
    const float ls = lsum + __shfl_xor(lsum, 32, 64);
    const float rq = 1.0f / ls;

    // epilogue: O^T regs -> O[q][d], d = dt*32 + 8*g + 4*hi + (0..3)
    __hip_bfloat16* Orow = O + (((size_t)b_ * SL + qg) * NH + h) * DK;
    #pragma unroll
    for (int g = 0; g < 4; g++) {
        uint2 pk0, pk1;
        pk0.x = cvt_pk_bf16(o0[4*g+0]*rq, o0[4*g+1]*rq);
        pk0.y = cvt_pk_bf16(o0[4*g+2]*rq, o0[4*g+3]*rq);
        pk1.x = cvt_pk_bf16(o1[4*g+0]*rq, o1[4*g+1]*rq);
        pk1.y = cvt_pk_bf16(o1[4*g+2]*rq, o1[4*g+3]*rq);
        *reinterpret_cast<uint2*>(Orow + 8*g + 4*hi)      = pk0;
        *reinterpret_cast<uint2*>(Orow + 32 + 8*g + 4*hi) = pk1;
    }
}

// ---------------------------------------------------------------------------
// ws layout (fast path, 72 MiB): [q 16M][k 16M][v 16M][xb 16M][wq 2M][wk 2M]
// [wv 2M][wo 2M]. Attention O reuses xb (dead after projections); Wo GEMM
// writes fp32 directly to d_out (no copy).
// ---------------------------------------------------------------------------
extern "C" void kernel_launch(void* const* d_in, const int* in_sizes, int n_in,
                              void* d_out, int out_size, void* d_ws, size_t ws_size,
                              hipStream_t stream)
{
    const float* x  = (const float*)d_in[0];
    const float* Wq = (const float*)d_in[1];
    const float* Wk = (const float*)d_in[2];
    const float* Wv = (const float*)d_in[3];
    const float* Wo = (const float*)d_in[4];

    __hip_bfloat16* q_ws = (__hip_bfloat16*)d_ws;
    __hip_bfloat16* k_ws = q_ws + QKV_ELEMS;
    __hip_bfloat16* v_ws = k_ws + QKV_ELEMS;

    const dim3 gb(256);
    const size_t FAST_WS = (3 * QKV_ELEMS + QKV_ELEMS + 4 * (size_t)DM * DM)
                           * sizeof(__hip_bfloat16);   // 72 MiB

    if (ws_size >= FAST_WS) {
        __hip_bfloat16* xb  = v_ws + QKV_ELEMS;
        __hip_bfloat16* wqb = xb  + QKV_ELEMS;        // [Wq;Wk;Wv] contiguous
        __hip_bfloat16* wob = wqb + 3 * (size_t)DM * DM;

        cvt_all<<<12288, 256, 0, stream>>>(x, Wq, Wk, Wv, Wo, xb);

        gemm_qkv<<<dim3(64, 24), gb, 0, stream>>>(xb, wqb, q_ws, k_ws, v_ws);

        attn_causal<<<dim3(16, BB*NH), 256, 0, stream>>>(q_ws, k_ws, v_ws, xb);

        gemm_wo<<<dim3(64, 8), gb, 0, stream>>>(xb, wob, (float*)d_out);
    } else {
        __hip_bfloat16* obuf = (__hip_bfloat16*)d_out;
        float*          fbuf = (float*)d_ws;
        const dim3 gg(64, 8);
        gemm_bt<false, 0><<<gg, gb, 0, stream>>>(x, Wq, q_ws, SC_LOG2E);
        gemm_bt<false, 0><<<gg, gb, 0, stream>>>(x, Wk, k_ws, 1.0f);
        gemm_bt<false, 1><<<gg, gb, 0, stream>>>(x, Wv, v_ws, 1.0f);
        attn_causal<<<dim3(16, BB*NH), 256, 0, stream>>>(q_ws, k_ws, v_ws, obuf);
        gemm_bt<true, 2><<<gg, gb, 0, stream>>>(obuf, Wo, fbuf, 1.0f);
        (void)hipMemcpyAsync(d_out, fbuf, QKV_ELEMS * sizeof(float),
                             hipMemcpyDeviceToDevice, stream);
    }
}

// Round 13
// 244.257 us; speedup vs baseline: 1.0843x; 1.0843x over previous
//
#include <hip/hip_runtime.h>
#include <hip/hip_bf16.h>

typedef __attribute__((ext_vector_type(8))) short short8;
typedef __attribute__((ext_vector_type(2))) float f32x2;
typedef __attribute__((ext_vector_type(4))) float f32x4;
typedef __attribute__((ext_vector_type(16))) float f32x16;

static constexpr int DM = 1024;   // d_model
static constexpr int NH = 16;     // heads
static constexpr int DK = 64;     // head dim
static constexpr int SL = 2048;   // seq len
static constexpr int BB = 4;      // batch
static constexpr size_t QKV_ELEMS = (size_t)BB * NH * SL * DK;  // 8388608
static constexpr float NEG_BIG = -30000.0f;          // exp2 -> 0
static constexpr float SC_LOG2E = 0.125f * 1.44269504088896340736f; // /sqrt(64)*log2(e)

union PackB { __hip_bfloat16 h[8]; uint4 u; };
union Pack4 { __hip_bfloat16 h[4]; uint2 u; };

// async global->LDS, 16 B per lane (dest = wave-uniform base + lane*16)
typedef __attribute__((address_space(1))) unsigned int gu32;
typedef __attribute__((address_space(3))) unsigned int lu32;
__device__ __forceinline__ void async_copy16(const void* g, void* l) {
    __builtin_amdgcn_global_load_lds((gu32*)g, (lu32*)l, 16, 0, 0);
}

// pack two f32 -> two bf16 in one u32 (low = first arg)
__device__ __forceinline__ unsigned cvt_pk_bf16(float lo, float hi) {
    unsigned r;
    asm("v_cvt_pk_bf16_f32 %0, %1, %2" : "=v"(r) : "v"(lo), "v"(hi));
    return r;
}
// swap: a.hi <-> b.lo  (new_a[l>=32]=b[l-32], new_b[l<32]=a[l+32])
__device__ __forceinline__ void pl32_swap(unsigned &a, unsigned &b) {
    asm("v_permlane32_swap_b32 %0, %1" : "+v"(a), "+v"(b));
}

// ---------------------------------------------------------------------------
// Bulk fp32 -> bf16 convert: x (8M elems) then Wq,Wk,Wv,Wo (1M each) into one
// contiguous bf16 region. One float4 per thread.
// ---------------------------------------------------------------------------
__global__ __launch_bounds__(256)
void cvt_all(const float* __restrict__ x,
             const float* __restrict__ wq, const float* __restrict__ wk,
             const float* __restrict__ wv, const float* __restrict__ wo,
             __hip_bfloat16* __restrict__ dst)
{
    const size_t i = (size_t)blockIdx.x * 256 + threadIdx.x;  // float4 index
    const float* src; size_t local;
    if (i < 2097152) { src = x; local = i; }
    else {
        const size_t j = i - 2097152;
        const int r = (int)(j >> 18);           // 262144 float4 per W
        local = j & 262143;
        src = (r == 0) ? wq : (r == 1) ? wk : (r == 2) ? wv : wo;
    }
    float4 f = reinterpret_cast<const float4*>(src)[local];
    Pack4 p;
    p.h[0] = __float2bfloat16(f.x); p.h[1] = __float2bfloat16(f.y);
    p.h[2] = __float2bfloat16(f.z); p.h[3] = __float2bfloat16(f.w);
    reinterpret_cast<uint2*>(dst)[i] = p.u;
}

// ---------------------------------------------------------------------------
// Fused QKV projection, BK=64, 2-phase double-buffered, 128^2 / 256 thr
// (FROZEN — measured 82.6-84.9 us at healthy clocks). Q PRE-SCALED.
// ---------------------------------------------------------------------------
__global__ __launch_bounds__(256)
void gemm_qkv(const __hip_bfloat16* __restrict__ A,
              const __hip_bfloat16* __restrict__ W,
              __hip_bfloat16* __restrict__ q_out,
              __hip_bfloat16* __restrict__ k_out,
              __hip_bfloat16* __restrict__ v_out)
{
    __shared__ __hip_bfloat16 As[2][128 * 64];
    __shared__ __hip_bfloat16 Bs[2][128 * 64];
    const int tid  = threadIdx.x;
    const int m0   = blockIdx.x * 128;
    const int n0   = blockIdx.y * 128;
    const int w    = tid >> 6;
    const int lane = tid & 63;
    const int quad = lane >> 4;
    const int ln   = lane & 15;
    const int wm   = (w & 1) * 64;
    const int wn   = (w >> 1) * 64;
    const int srow = lane >> 3;                    // 0..7
    const int sch  = ((lane & 7) ^ srow) * 8;      // swizzled source chunk

    f32x4 acc[4][4] = {};

    auto stage = [&](int buf, int k0) {
        #pragma unroll
        for (int j = 0; j < 4; j++) {
            const int rbase = w * 32 + j * 8;      // stripe-aligned
            async_copy16(A + (size_t)(m0 + rbase + srow) * DM + k0 + sch,
                         &As[buf][rbase * 64]);
            async_copy16(W + (size_t)(n0 + rbase + srow) * DM + k0 + sch,
                         &Bs[buf][rbase * 64]);
        }
    };

    constexpr int NT = DM / 64;   // 16
    stage(0, 0);
    asm volatile("s_waitcnt vmcnt(0)" ::: "memory");
    __syncthreads();

    int cur = 0;
    for (int t = 0; t < NT; ++t) {
        if (t + 1 < NT) stage(cur ^ 1, (t + 1) * 64);

        #pragma unroll
        for (int ks = 0; ks < 2; ks++) {
            short8 a[4], b[4];
            #pragma unroll
            for (int i = 0; i < 4; i++)
                a[i] = *reinterpret_cast<const short8*>(
                    &As[cur][(wm + i*16 + ln) * 64 + (((ks*4 + quad) ^ (ln & 7)) * 8)]);
            #pragma unroll
            for (int j = 0; j < 4; j++)
                b[j] = *reinterpret_cast<const short8*>(
                    &Bs[cur][(wn + j*16 + ln) * 64 + (((ks*4 + quad) ^ (ln & 7)) * 8)]);
            __builtin_amdgcn_s_setprio(1);
            #pragma unroll
            for (int i = 0; i < 4; i++)
                #pragma unroll
                for (int j = 0; j < 4; j++)
                    acc[i][j] = __builtin_amdgcn_mfma_f32_16x16x32_bf16(a[i], b[j], acc[i][j], 0, 0, 0);
            __builtin_amdgcn_s_setprio(0);
        }

        if (t + 1 < NT) {
            asm volatile("s_waitcnt vmcnt(0)" ::: "memory");
            __syncthreads();
        }
        cur ^= 1;
    }

    // Epilogue: C/D layout col=lane&15, row=quad*4+reg  [m89/m91]
    #pragma unroll
    for (int i = 0; i < 4; i++) {
        #pragma unroll
        for (int j = 0; j < 4; j++) {
            #pragma unroll
            for (int r = 0; r < 4; r++) {
                const int m = m0 + wm + i*16 + quad*4 + r;
                const int n = n0 + wn + j*16 + ln;     // 0..3071
                const int b_ = m >> 11;
                const int s  = m & 2047;
                const int which = n >> 10;             // 0=Q 1=K 2=V
                const int nn = n & 1023;
                const int h  = nn >> 6;
                const int d  = nn & 63;
                if (which == 0) {
                    const __hip_bfloat16 v = __float2bfloat16(acc[i][j][r] * SC_LOG2E);
                    q_out[((size_t)((b_*NH + h)*SL + s))*DK + d] = v;
                } else if (which == 1) {
                    const __hip_bfloat16 v = __float2bfloat16(acc[i][j][r]);
                    k_out[((size_t)((b_*NH + h)*SL + s))*DK + d] = v;
                } else {
                    const __hip_bfloat16 v = __float2bfloat16(acc[i][j][r]);
                    v_out[((size_t)((b_*NH + h)*DK + d))*SL + s] = v;
                }
            }
        }
    }
}

// ---------------------------------------------------------------------------
// Pure-bf16 GEMM (final projection), 2-phase dbuf (frozen).
// ---------------------------------------------------------------------------
__global__ __launch_bounds__(256)
void gemm_wo(const __hip_bfloat16* __restrict__ A,
             const __hip_bfloat16* __restrict__ W,
             float* __restrict__ outp)
{
    __shared__ __hip_bfloat16 As[2][128 * 64];
    __shared__ __hip_bfloat16 Bs[2][128 * 64];
    const int tid  = threadIdx.x;
    const int m0   = blockIdx.x * 128;
    const int n0   = blockIdx.y * 128;
    const int w    = tid >> 6;
    const int lane = tid & 63;
    const int quad = lane >> 4;
    const int ln   = lane & 15;
    const int wm   = (w & 1) * 64;
    const int wn   = (w >> 1) * 64;
    const int srow = lane >> 3;
    const int sch  = ((lane & 7) ^ srow) * 8;

    f32x4 acc[4][4] = {};

    auto stage = [&](int buf, int k0) {
        #pragma unroll
        for (int j = 0; j < 4; j++) {
            const int rbase = w * 32 + j * 8;
            async_copy16(A + (size_t)(m0 + rbase + srow) * DM + k0 + sch,
                         &As[buf][rbase * 64]);
            async_copy16(W + (size_t)(n0 + rbase + srow) * DM + k0 + sch,
                         &Bs[buf][rbase * 64]);
        }
    };

    constexpr int NT = DM / 64;
    stage(0, 0);
    asm volatile("s_waitcnt vmcnt(0)" ::: "memory");
    __syncthreads();

    int cur = 0;
    for (int t = 0; t < NT; ++t) {
        if (t + 1 < NT) stage(cur ^ 1, (t + 1) * 64);

        #pragma unroll
        for (int ks = 0; ks < 2; ks++) {
            short8 a[4], b[4];
            #pragma unroll
            for (int i = 0; i < 4; i++)
                a[i] = *reinterpret_cast<const short8*>(
                    &As[cur][(wm + i*16 + ln) * 64 + (((ks*4 + quad) ^ (ln & 7)) * 8)]);
            #pragma unroll
            for (int j = 0; j < 4; j++)
                b[j] = *reinterpret_cast<const short8*>(
                    &Bs[cur][(wn + j*16 + ln) * 64 + (((ks*4 + quad) ^ (ln & 7)) * 8)]);
            __builtin_amdgcn_s_setprio(1);
            #pragma unroll
            for (int i = 0; i < 4; i++)
                #pragma unroll
                for (int j = 0; j < 4; j++)
                    acc[i][j] = __builtin_amdgcn_mfma_f32_16x16x32_bf16(a[i], b[j], acc[i][j], 0, 0, 0);
            __builtin_amdgcn_s_setprio(0);
        }

        if (t + 1 < NT) {
            asm volatile("s_waitcnt vmcnt(0)" ::: "memory");
            __syncthreads();
        }
        cur ^= 1;
    }

    #pragma unroll
    for (int i = 0; i < 4; i++)
        #pragma unroll
        for (int j = 0; j < 4; j++)
            #pragma unroll
            for (int r = 0; r < 4; r++) {
                const int m = m0 + wm + i*16 + quad*4 + r;
                const int n = n0 + wn + j*16 + ln;
                outp[(size_t)m * DM + n] = acc[i][j][r];
            }
}

// ---------------------------------------------------------------------------
// Fallback GEMM: fp32 inputs, convert during staging. scl folds the softmax
// scale into Q (attn expects pre-scaled Q).
// ---------------------------------------------------------------------------
template<bool A_BF16, int MODE>
__global__ __launch_bounds__(256)
void gemm_bt(const void* __restrict__ Ap,
             const float* __restrict__ W,
             void* __restrict__ outp, float scl)
{
    __shared__ __hip_bfloat16 As[128][40];
    __shared__ __hip_bfloat16 Bs[128][40];
    const int tid  = threadIdx.x;
    const int m0   = blockIdx.x * 128;
    const int n0   = blockIdx.y * 128;
    const int w    = tid >> 6;
    const int lane = tid & 63;
    const int quad = lane >> 4;
    const int ln   = lane & 15;
    const int wm   = (w & 1) * 64;
    const int wn   = (w >> 1) * 64;
    const int lr   = tid >> 1;
    const int lc   = (tid & 1) * 16;

    f32x4 acc[4][4] = {};

    for (int k0 = 0; k0 < DM; k0 += 32) {
        if (A_BF16) {
            const uint4* ap = reinterpret_cast<const uint4*>(
                (const __hip_bfloat16*)Ap + (size_t)(m0 + lr) * DM + k0 + lc);
            uint4 a0 = ap[0], a1 = ap[1];
            *reinterpret_cast<uint4*>(&As[lr][lc])     = a0;
            *reinterpret_cast<uint4*>(&As[lr][lc + 8]) = a1;
        } else {
            const float4* ap = reinterpret_cast<const float4*>(
                (const float*)Ap + (size_t)(m0 + lr) * DM + k0 + lc);
            float4 f0 = ap[0], f1 = ap[1], f2 = ap[2], f3 = ap[3];
            PackB p0, p1;
            p0.h[0] = __float2bfloat16(f0.x); p0.h[1] = __float2bfloat16(f0.y);
            p0.h[2] = __float2bfloat16(f0.z); p0.h[3] = __float2bfloat16(f0.w);
            p0.h[4] = __float2bfloat16(f1.x); p0.h[5] = __float2bfloat16(f1.y);
            p0.h[6] = __float2bfloat16(f1.z); p0.h[7] = __float2bfloat16(f1.w);
            p1.h[0] = __float2bfloat16(f2.x); p1.h[1] = __float2bfloat16(f2.y);
            p1.h[2] = __float2bfloat16(f2.z); p1.h[3] = __float2bfloat16(f2.w);
            p1.h[4] = __float2bfloat16(f3.x); p1.h[5] = __float2bfloat16(f3.y);
            p1.h[6] = __float2bfloat16(f3.z); p1.h[7] = __float2bfloat16(f3.w);
            *reinterpret_cast<uint4*>(&As[lr][lc])     = p0.u;
            *reinterpret_cast<uint4*>(&As[lr][lc + 8]) = p1.u;
        }
        {
            const float4* wp = reinterpret_cast<const float4*>(
                W + (size_t)(n0 + lr) * DM + k0 + lc);
            float4 f0 = wp[0], f1 = wp[1], f2 = wp[2], f3 = wp[3];
            PackB p0, p1;
            p0.h[0] = __float2bfloat16(f0.x); p0.h[1] = __float2bfloat16(f0.y);
            p0.h[2] = __float2bfloat16(f0.z); p0.h[3] = __float2bfloat16(f0.w);
            p0.h[4] = __float2bfloat16(f1.x); p0.h[5] = __float2bfloat16(f1.y);
            p0.h[6] = __float2bfloat16(f1.z); p0.h[7] = __float2bfloat16(f1.w);
            p1.h[0] = __float2bfloat16(f2.x); p1.h[1] = __float2bfloat16(f2.y);
            p1.h[2] = __float2bfloat16(f2.z); p1.h[3] = __float2bfloat16(f2.w);
            p1.h[4] = __float2bfloat16(f3.x); p1.h[5] = __float2bfloat16(f3.y);
            p1.h[6] = __float2bfloat16(f3.z); p1.h[7] = __float2bfloat16(f3.w);
            *reinterpret_cast<uint4*>(&Bs[lr][lc])     = p0.u;
            *reinterpret_cast<uint4*>(&Bs[lr][lc + 8]) = p1.u;
        }
        __syncthreads();

        short8 a[4], b[4];
        #pragma unroll
        for (int i = 0; i < 4; i++)
            a[i] = *reinterpret_cast<const short8*>(&As[wm + i*16 + ln][quad*8]);
        #pragma unroll
        for (int j = 0; j < 4; j++)
            b[j] = *reinterpret_cast<const short8*>(&Bs[wn + j*16 + ln][quad*8]);
        #pragma unroll
        for (int i = 0; i < 4; i++)
            #pragma unroll
            for (int j = 0; j < 4; j++)
                acc[i][j] = __builtin_amdgcn_mfma_f32_16x16x32_bf16(a[i], b[j], acc[i][j], 0, 0, 0);
        __syncthreads();
    }

    #pragma unroll
    for (int i = 0; i < 4; i++) {
        #pragma unroll
        for (int j = 0; j < 4; j++) {
            #pragma unroll
            for (int r = 0; r < 4; r++) {
                const int m = m0 + wm + i*16 + quad*4 + r;
                const int n = n0 + wn + j*16 + ln;
                const float v = acc[i][j][r] * scl;
                if (MODE == 2) {
                    ((float*)outp)[(size_t)m * DM + n] = v;
                } else {
                    const int b_ = m >> 11;
                    const int s  = m & 2047;
                    const int h  = n >> 6;
                    const int d  = n & 63;
                    size_t idx;
                    if (MODE == 0) idx = ((size_t)((b_*NH + h)*SL + s))*DK + d;
                    else           idx = ((size_t)((b_*NH + h)*DK + d))*SL + s;
                    ((__hip_bfloat16*)outp)[idx] = __float2bfloat16(v);
                }
            }
        }
    }
}

// ---------------------------------------------------------------------------
// Causal flash attention, 32x32 swapped-operand form (BEST-KNOWN round-11
// config, measured 244.5 us total). Double-buffered gload_lds staging with
// counted vmcnt(8); both-sides XOR swizzle; XCD-locality remap. Round-12's
// single-V-buffer pipeline measured on a throttled chip (identical qkv code
// read +30%) — unvalidated; reverting to the measured best.
// ---------------------------------------------------------------------------
__global__ __launch_bounds__(256)
void attn_causal(const __hip_bfloat16* __restrict__ Q,
                 const __hip_bfloat16* __restrict__ K,
                 const __hip_bfloat16* __restrict__ Vt,
                 __hip_bfloat16* __restrict__ O)
{
    __shared__ __hip_bfloat16 Ks[2][128 * 64];   // [k][d] linear, src-swizzled
    __shared__ __hip_bfloat16 Vs[2][64 * 128];   // [d][k] linear, src-swizzled

    const int tid  = threadIdx.x;
    const int w    = tid >> 6;
    const int lane = tid & 63;
    const int ln32 = lane & 31;
    const int hi   = lane >> 5;

    // XCD-locality remap (bijective over 512 blocks)
    const int dd   = (int)blockIdx.y * 8 + (int)blockIdx.x;
    const int xcd  = dd & 7;
    const int kk   = dd >> 3;
    const int qblk = kk & 7;
    const int bh   = xcd + 8 * (kk >> 3);

    const int b_   = bh >> 4;
    const int h    = bh & 15;

    const __hip_bfloat16* Qb = Q  + (size_t)bh * SL * DK;
    const __hip_bfloat16* Kb = K  + (size_t)bh * SL * DK;
    const __hip_bfloat16* Vb = Vt + (size_t)bh * DK * SL;

    auto stageKV = [&](int buf, int k0) {
        #pragma unroll
        for (int j = 0; j < 4; j++) {            // K: 128 rows x 64
            const int rb = w * 32 + j * 8;
            const int r  = rb + (lane >> 3);
            async_copy16(Kb + (size_t)(k0 + r) * DK + (((lane & 7) ^ (r & 7)) * 8),
                         &Ks[buf][rb * 64]);
        }
        #pragma unroll
        for (int j = 0; j < 4; j++) {            // V: 64 rows x 128
            const int db = w * 16 + j * 4;
            const int d  = db + (lane >> 4);
            async_copy16(Vb + (size_t)d * SL + k0 + (((lane & 15) ^ (d & 7)) * 8),
                         &Vs[buf][db * 128]);
        }
    };

    for (int pass = 0; pass < 2; ++pass) {
        const int qt    = (pass == 0) ? qblk : 15 - qblk;
        const int q0    = qt * 128;
        const int qbase = q0 + w * 32;
        const int qg    = qbase + ln32;       // this lane's q row

        short8 qf[4];
        #pragma unroll
        for (int dt = 0; dt < 4; dt++)
            qf[dt] = *reinterpret_cast<const short8*>(
                Qb + (size_t)qg * DK + dt*16 + hi*8);

        f32x16 o0 = {}, o1 = {};
        f32x2 ls2 = {0.f, 0.f};

        const int npair = qt + 1;            // 128-k pairs

        stageKV(0, 0);                       // prologue

        for (int ip = 0; ip < npair; ++ip) {
            const int cur = ip & 1;
            if (ip + 1 < npair) {
                stageKV(cur ^ 1, (ip + 1) * 128);
                // cur's 8 loads done; nxt's 8 stay in flight across barrier
                asm volatile("s_waitcnt vmcnt(8)" ::: "memory");
            } else {
                asm volatile("s_waitcnt vmcnt(0)" ::: "memory");
            }
            __builtin_amdgcn_sched_barrier(0);
            __builtin_amdgcn_s_barrier();
            __builtin_amdgcn_sched_barrier(0);

            const int k0 = ip * 128;
            #pragma unroll
            for (int hf = 0; hf < 2; hf++) {
                const int kh0 = k0 + hf * 64;
                if (kh0 > qbase + 31) continue;   // wave-uniform: fully masked

                // ---- QK^T (swapped): S[k][q]; Q pre-scaled ----
                f32x16 s0 = {}, s1 = {};
                __builtin_amdgcn_s_setprio(1);
                #pragma unroll
                for (int dt = 0; dt < 4; dt++) {
                    const int r0 = hf*64 + ln32;
                    const int ch = (dt*2 + hi) ^ (ln32 & 7);
                    short8 kf0 = *reinterpret_cast<const short8*>(&Ks[cur][r0*64 + ch*8]);
                    short8 kf1 = *reinterpret_cast<const short8*>(&Ks[cur][(r0 + 32)*64 + ch*8]);
                    s0 = __builtin_amdgcn_mfma_f32_32x32x16_bf16(kf0, qf[dt], s0, 0, 0, 0);
                    s1 = __builtin_amdgcn_mfma_f32_32x32x16_bf16(kf1, qf[dt], s1, 0, 0, 0);
                }
                __builtin_amdgcn_s_setprio(0);

                // ---- softmax numerator (in place) ----
                const bool dodiag = (kh0 + 63 > qbase);
                if (dodiag) {
                    #pragma unroll
                    for (int r = 0; r < 16; r++) {
                        const int km = (r & 3) + 8*(r >> 2) + 4*hi;
                        float v0 = s0[r];
                        float v1 = s1[r];
                        if (kh0 + km      > qg) v0 = NEG_BIG;
                        if (kh0 + 32 + km > qg) v1 = NEG_BIG;
                        const float p0 = __builtin_amdgcn_exp2f(v0);
                        const float p1 = __builtin_amdgcn_exp2f(v1);
                        s0[r] = p0; s1[r] = p1;
                        ls2.x += p0; ls2.y += p1;
                    }
                } else {
                    #pragma unroll
                    for (int r = 0; r < 16; r++) {
                        const float p0 = __builtin_amdgcn_exp2f(s0[r]);
                        const float p1 = __builtin_amdgcn_exp2f(s1[r]);
                        s0[r] = p0; s1[r] = p1;
                        ls2.x += p0; ls2.y += p1;
                    }
                }

                // ---- P fragments (cvt_pk + permlane32_swap) + PV ----
                __builtin_amdgcn_s_setprio(1);
                #pragma unroll
                for (int c = 0; c < 4; c++) {
                    const int R = 8 * (c & 1);
                    unsigned x0, x1, y0, y1;
                    if (c < 2) {
                        x0 = cvt_pk_bf16(s0[R+0], s0[R+1]);
                        x1 = cvt_pk_bf16(s0[R+2], s0[R+3]);
                        y0 = cvt_pk_bf16(s0[R+4], s0[R+5]);
                        y1 = cvt_pk_bf16(s0[R+6], s0[R+7]);
                    } else {
                        x0 = cvt_pk_bf16(s1[R+0], s1[R+1]);
                        x1 = cvt_pk_bf16(s1[R+2], s1[R+3]);
                        y0 = cvt_pk_bf16(s1[R+4], s1[R+5]);
                        y1 = cvt_pk_bf16(s1[R+6], s1[R+7]);
                    }
                    pl32_swap(x0, y0);
                    pl32_swap(x1, y1);
                    union { unsigned u[4]; short8 s8; } pf;
                    pf.u[0] = x0; pf.u[1] = x1; pf.u[2] = y0; pf.u[3] = y1;
                    const int vc = (hf*8 + c*2 + hi) ^ (ln32 & 7);
                    short8 vf0 = *reinterpret_cast<const short8*>(&Vs[cur][ln32*128 + vc*8]);
                    short8 vf1 = *reinterpret_cast<const short8*>(&Vs[cur][(32 + ln32)*128 + vc*8]);
                    o0 = __builtin_amdgcn_mfma_f32_32x32x16_bf16(vf0, pf.s8, o0, 0, 0, 0);
                    o1 = __builtin_amdgcn_mfma_f32_32x32x16_bf16(vf1, pf.s8, o1, 0, 0, 0);
                }
                __builtin_amdgcn_s_setprio(0);
            }
            // reads of cur done before iter ip+1 stages into cur (2 iters on)
            __builtin_amdgcn_s_barrier();
        }

        // full row-sum: this lane's partials + its hi/lo partner
        float lsum = ls2.x + ls2.y;
        const float ls = lsum + __shfl_xor(lsum, 32, 64);
        const float rq = 1.0f / ls;

        // epilogue: O^T regs -> O[q][d], d = dt*32 + 8*g + 4*hi + (0..3)
        __hip_bfloat16* Orow = O + (((size_t)b_ * SL + qg) * NH + h) * DK;
        #pragma unroll
        for (int g = 0; g < 4; g++) {
            uint2 pk0, pk1;
            pk0.x = cvt_pk_bf16(o0[4*g+0]*rq, o0[4*g+1]*rq);
            pk0.y = cvt_pk_bf16(o0[4*g+2]*rq, o0[4*g+3]*rq);
            pk1.x = cvt_pk_bf16(o1[4*g+0]*rq, o1[4*g+1]*rq);
            pk1.y = cvt_pk_bf16(o1[4*g+2]*rq, o1[4*g+3]*rq);
            *reinterpret_cast<uint2*>(Orow + 8*g + 4*hi)      = pk0;
            *reinterpret_cast<uint2*>(Orow + 32 + 8*g + 4*hi) = pk1;
        }
    }
}

// ---------------------------------------------------------------------------
// ws layout (fast path, 72 MiB): [q 16M][k 16M][v 16M][xb 16M][wq 2M][wk 2M]
// [wv 2M][wo 2M]. Attention O reuses xb (dead after projections); Wo GEMM
// writes fp32 directly to d_out (no copy).
// ---------------------------------------------------------------------------
extern "C" void kernel_launch(void* const* d_in, const int* in_sizes, int n_in,
                              void* d_out, int out_size, void* d_ws, size_t ws_size,
                              hipStream_t stream)
{
    const float* x  = (const float*)d_in[0];
    const float* Wq = (const float*)d_in[1];
    const float* Wk = (const float*)d_in[2];
    const float* Wv = (const float*)d_in[3];
    const float* Wo = (const float*)d_in[4];

    __hip_bfloat16* q_ws = (__hip_bfloat16*)d_ws;
    __hip_bfloat16* k_ws = q_ws + QKV_ELEMS;
    __hip_bfloat16* v_ws = k_ws + QKV_ELEMS;

    const dim3 gb(256);
    const size_t FAST_WS = (3 * QKV_ELEMS + QKV_ELEMS + 4 * (size_t)DM * DM)
                           * sizeof(__hip_bfloat16);   // 72 MiB

    if (ws_size >= FAST_WS) {
        __hip_bfloat16* xb  = v_ws + QKV_ELEMS;
        __hip_bfloat16* wqb = xb  + QKV_ELEMS;        // [Wq;Wk;Wv] contiguous
        __hip_bfloat16* wob = wqb + 3 * (size_t)DM * DM;

        cvt_all<<<12288, 256, 0, stream>>>(x, Wq, Wk, Wv, Wo, xb);

        gemm_qkv<<<dim3(64, 24), gb, 0, stream>>>(xb, wqb, q_ws, k_ws, v_ws);

        attn_causal<<<dim3(8, BB*NH), 256, 0, stream>>>(q_ws, k_ws, v_ws, xb);

        gemm_wo<<<dim3(64, 8), gb, 0, stream>>>(xb, wob, (float*)d_out);
    } else {
        __hip_bfloat16* obuf = (__hip_bfloat16*)d_out;
        float*          fbuf = (float*)d_ws;
        const dim3 gg(64, 8);
        gemm_bt<false, 0><<<gg, gb, 0, stream>>>(x, Wq, q_ws, SC_LOG2E);
        gemm_bt<false, 0><<<gg, gb, 0, stream>>>(x, Wk, k_ws, 1.0f);
        gemm_bt<false, 1><<<gg, gb, 0, stream>>>(x, Wv, v_ws, 1.0f);
        attn_causal<<<dim3(8, BB*NH), 256, 0, stream>>>(q_ws, k_ws, v_ws, obuf);
        gemm_bt<true, 2><<<gg, gb, 0, stream>>>(obuf, Wo, fbuf, 1.0f);
        (void)hipMemcpyAsync(d_out, fbuf, QKV_ELEMS * sizeof(float),
                             hipMemcpyDeviceToDevice, stream);
    }
}